// Round 14
// baseline (8404.749 us; speedup 1.0000x reference)
//
#include <hip/hip_runtime.h>
#include <math.h>

#define KD    1024   // k
#define BATCH 2048
#define XD    784
#define YD    10

typedef _Float16 f16;
typedef _Float16 f16x8 __attribute__((ext_vector_type(8)));
typedef _Float16 f16x4 __attribute__((ext_vector_type(4)));
typedef float    f32x4 __attribute__((ext_vector_type(4)));

#define TS  64
#define KS  32
#define LDP 68

// ---------------------------------------------------------------------------
// atb tile body: C[i][j] = sum_d A[d][i]*B[d][j]  (A:[K x M], B:[K x N])
// ---------------------------------------------------------------------------
__device__ __forceinline__ void atb_body(const float* __restrict__ A,
                                         const float* __restrict__ B,
                                         float* __restrict__ C,
                                         int M, int N, int K, int bx, int by,
                                         float (*As)[LDP], float (*Bs)[LDP])
{
    const int tid = threadIdx.x;
    const int tx = tid & 15, ty = tid >> 4;
    const int i0 = by * TS, j0 = bx * TS;
    float acc[4][4] = {};

    for (int k0 = 0; k0 < K; k0 += KS) {
#pragma unroll
        for (int q = 0; q < 2; ++q) {
            const int f  = tid + q * 256;
            const int kr = f >> 4;
            const int cc = (f & 15) << 2;
            float4 av = make_float4(0.f, 0.f, 0.f, 0.f);
            float4 bv = av;
            if (k0 + kr < K) {
                av = *(const float4*)(A + (size_t)(k0 + kr) * M + i0 + cc);
                bv = *(const float4*)(B + (size_t)(k0 + kr) * N + j0 + cc);
            }
            *(float4*)&As[kr][cc] = av;
            *(float4*)&Bs[kr][cc] = bv;
        }
        __syncthreads();
#pragma unroll
        for (int kk = 0; kk < KS; ++kk) {
            const float4 a4 = *(const float4*)&As[kk][ty << 2];
            const float4 b4 = *(const float4*)&Bs[kk][tx << 2];
            const float a[4] = {a4.x, a4.y, a4.z, a4.w};
            const float b[4] = {b4.x, b4.y, b4.z, b4.w};
#pragma unroll
            for (int r = 0; r < 4; ++r)
#pragma unroll
                for (int c = 0; c < 4; ++c)
                    acc[r][c] = fmaf(a[r], b[c], acc[r][c]);
        }
        __syncthreads();
    }
#pragma unroll
    for (int r = 0; r < 4; ++r) {
        float4 o = make_float4(acc[r][0], acc[r][1], acc[r][2], acc[r][3]);
        *(float4*)(C + (size_t)(i0 + (ty << 2) + r) * N + j0 + (tx << 2)) = o;
    }
}

// ---------------------------------------------------------------------------
// Fused setup (one launch): blocks [0,256) WtW = Wx^T Wx; [256,768) XtW = x^T Wx;
// [768,1792) h_init -> f16; block 1792: power-iteration init vector.
// ---------------------------------------------------------------------------
__global__ __launch_bounds__(256) void setup_fused(const float* __restrict__ x,
                                                   const float* __restrict__ Wx,
                                                   const float* __restrict__ h_init,
                                                   float* __restrict__ WtW,
                                                   float* __restrict__ XtW,
                                                   f16* __restrict__ h0f,
                                                   float* __restrict__ w0)
{
    __shared__ float As[KS][LDP];
    __shared__ float Bs[KS][LDP];
    const int blk = blockIdx.x;
    if (blk < 256) {
        atb_body(Wx, Wx, WtW, KD, KD, XD, blk & 15, blk >> 4, As, Bs);
    } else if (blk < 768) {
        const int l = blk - 256;
        atb_body(x, Wx, XtW, BATCH, KD, XD, l & 15, l >> 4, As, Bs);
    } else if (blk < 1792) {
        const int i = (blk - 768) * 256 + threadIdx.x;     // x8 groups, 262144 total
        const f32x4 a = ((const f32x4*)h_init)[2 * i];
        const f32x4 b = ((const f32x4*)h_init)[2 * i + 1];
        f16x8 o;
#pragma unroll
        for (int j = 0; j < 4; ++j) { o[j] = (f16)a[j]; o[j + 4] = (f16)b[j]; }
        ((f16x8*)h0f)[i] = o;
    } else {
        ((float4*)w0)[threadIdx.x] = make_float4(0.03125f, 0.03125f, 0.03125f, 0.03125f);
    }
}

// ---------------------------------------------------------------------------
// bhi = f16(256*WtW)   (512 blocks x 256 thr x 8 elems)
// ---------------------------------------------------------------------------
__global__ __launch_bounds__(256) void convert_bhi(const float* __restrict__ WtW,
                                                   f16* __restrict__ bhi)
{
    const int i = blockIdx.x * 256 + threadIdx.x;          // x8, 131072 total
    const f32x4 a = ((const f32x4*)WtW)[2 * i];
    const f32x4 b = ((const f32x4*)WtW)[2 * i + 1];
    f16x8 o;
#pragma unroll
    for (int j = 0; j < 4; ++j) {
        o[j]     = (f16)(256.0f * a[j]);
        o[j + 4] = (f16)(256.0f * b[j]);
    }
    ((f16x8*)bhi)[i] = o;
}

// ---------------------------------------------------------------------------
// PERSISTENT independent-rows FISTA: ONE normal launch runs all 60 iterations
// + the final ypred. FISTA rows are independent: block b owns rows [8b,8b+8)
// and never communicates with other blocks.
//   grad = y @ (256*WtW)f16 / 256 - XtW ; h' = max(y - grad*invL, 0);
//   y' = h' + cm*(h' - h)
// 256 blocks x 512 thr (8 waves). Wave w owns output cols [128w,128w+128)
// (8 frags of 16). B streamed DIRECT global->VGPR (k-contiguous via WtW
// symmetry), double-buffered per 64-k step, full 128B-line consumption.
// y lives in an LDS slab [8][1024] f16 (row stride 2064 B -> A-frag ds_reads
// conflict-free); h/y/acc/B in registers; XtW re-read from L2 per iteration.
// 2 block barriers per iteration, zero global traffic for h/y state.
// MFMA per-element k-order and epilogue arithmetic identical to round 13.
// ---------------------------------------------------------------------------
#define SLAB_STRIDE 2064   // bytes per slab row (1032 f16) -> conflict-free

__global__ __launch_bounds__(512, 2) void fista_rows(
    const f16* __restrict__ h0f,     // [BATCH][KD] f16 initial h (= y0)
    const f16* __restrict__ bhiP,    // f16(256*WtW) [KD][KD]
    const float* __restrict__ xtwP,  // XtW fp32 [BATCH][KD]
    const float* __restrict__ invLp,
    const float* __restrict__ Wy,    // [YD][KD] fp32
    float* __restrict__ out)         // [YD][BATCH]
{
    __shared__ char lds[16640];      // y slab 16512 B; ypred partials reuse

    const int t    = threadIdx.x;
    const int lane = t & 63;
    const int w    = t >> 6;         // wave 0..7 -> cols [128w, 128w+128)
    const int lg   = lane >> 4;      // 0..3 (acc row group; valid rows: lg<2)
    const int lr   = lane & 15;
    const int b    = blockIdx.x;     // rows [8b, 8b+8)
    const int row0 = b * 8;
    const int myrow = lg * 4;        // acc rows myrow..myrow+3 (valid if lg<2)

    // ---- slab fill: y0 = h0 (8 rows x 1024, 16 f16 per thread) ----
    {
        const int r = t >> 6, c = (t & 63) * 16;
        const f16x8 v0 = *(const f16x8*)(h0f + (size_t)(row0 + r) * KD + c);
        const f16x8 v1 = *(const f16x8*)(h0f + (size_t)(row0 + r) * KD + c + 8);
        *(f16x8*)(lds + r * SLAB_STRIDE + c * 2)      = v0;
        *(f16x8*)(lds + r * SLAB_STRIDE + c * 2 + 16) = v1;
    }

    // ---- register state: h, y in acc layout (col = 128w+16nf+lr, row = myrow+r)
    f16x4 hreg[8] = {};
    f16x4 yreg[8] = {};
    if (lg < 2) {
        const f16* hp = h0f + (size_t)(row0 + myrow) * KD + w * 128 + lr;
#pragma unroll
        for (int nf = 0; nf < 8; ++nf)
#pragma unroll
            for (int r = 0; r < 4; ++r) {
                const f16 v = hp[(size_t)r * KD + nf * 16];
                hreg[nf][r] = v;
                yreg[nf][r] = v;
            }
    }

    const float invL  = invLp[0];
    const float invLs = invL * 0.00390625f;   // invL/256 (fold WtW scale)

    // ---- B per-lane fragment bases (k-contiguous via symmetry) ----
    const f16* bbase[8];
#pragma unroll
    for (int nf = 0; nf < 8; ++nf)
        bbase[nf] = bhiP + (size_t)(w * 128 + nf * 16 + lr) * KD + 8 * lg;

    // A-frag base in slab: lane l -> row (l&7) [rows 8..15 duplicate 0..7],
    // k = kt2*64 + s*32 + 8*lg
    const char* abase = lds + (lane & 7) * SLAB_STRIDE + lg * 16;

    // preload B k-step 0 into buf 0
    f16x8 Bf[2][8][2];
#pragma unroll
    for (int nf = 0; nf < 8; ++nf) {
        Bf[0][nf][0] = *(const f16x8*)(bbase[nf]);
        Bf[0][nf][1] = *(const f16x8*)(bbase[nf] + 32);
    }

    __syncthreads();                 // slab ready

    float tt = 1.0f;
#pragma unroll 1
    for (int n = 0; n < 60; ++n) {
        if (n == 50) {               // phase-2 restart: t = 1, y = h
            tt = 1.0f;
            __syncthreads();
            if (lg < 2) {
#pragma unroll
                for (int nf = 0; nf < 8; ++nf)
#pragma unroll
                    for (int r = 0; r < 4; ++r) {
                        yreg[nf][r] = hreg[nf][r];
                        *(f16*)(lds + (myrow + r) * SLAB_STRIDE
                                    + (w * 128 + nf * 16 + lr) * 2) = yreg[nf][r];
                    }
            }
            __syncthreads();
        }
        const float t2 = __fmul_rn(tt, tt);
        const float tn = 0.5f * (1.0f + sqrtf(1.0f + __fmul_rn(4.0f, t2)));
        const float cm = (tt - 1.0f) / tn;

        // ---- GEMM: acc = y(rows) @ B  (no barriers; slab read-only) ----
        f32x4 acc[8] = {};
#pragma unroll
        for (int kt2 = 0; kt2 < 16; ++kt2) {
            const int cur = kt2 & 1, nxt = cur ^ 1;
            const int ko  = ((kt2 + 1) & 15) * 64;   // next k-step (wraps: B const)
#pragma unroll
            for (int nf = 0; nf < 8; ++nf) {
                Bf[nxt][nf][0] = *(const f16x8*)(bbase[nf] + ko);
                Bf[nxt][nf][1] = *(const f16x8*)(bbase[nf] + ko + 32);
            }
            const f16x8 A0 = *(const f16x8*)(abase + kt2 * 128);
            const f16x8 A1 = *(const f16x8*)(abase + kt2 * 128 + 64);
#pragma unroll
            for (int nf = 0; nf < 8; ++nf)
                acc[nf] = __builtin_amdgcn_mfma_f32_16x16x32_f16(A0, Bf[cur][nf][0], acc[nf], 0, 0, 0);
#pragma unroll
            for (int nf = 0; nf < 8; ++nf)
                acc[nf] = __builtin_amdgcn_mfma_f32_16x16x32_f16(A1, Bf[cur][nf][1], acc[nf], 0, 0, 0);
        }

        // ---- epilogue: prox + momentum, write new y to slab ----
        __syncthreads();             // all waves finished reading slab
        if (lg < 2) {
            const float* xb = xtwP + (size_t)(row0 + myrow) * KD + w * 128 + lr;
#pragma unroll
            for (int nf = 0; nf < 8; ++nf) {
#pragma unroll
                for (int r = 0; r < 4; ++r) {
                    const float av = acc[nf][r];
                    const float xv = xb[(size_t)r * KD + nf * 16];
                    const float yv = (float)yreg[nf][r];
                    const float hv = (float)hreg[nf][r];
                    const float t1 = fmaf(invL, xv, yv);
                    const float hn = fmaxf(fmaf(-invLs, av, t1), 0.f);
                    const float yn = fmaf(cm, hn - hv, hn);
                    hreg[nf][r] = (f16)hn;
                    yreg[nf][r] = (f16)yn;
                    *(f16*)(lds + (myrow + r) * SLAB_STRIDE
                                + (w * 128 + nf * 16 + lr) * 2) = yreg[nf][r];
                }
            }
        }
        __syncthreads();
        tt = tn;
    }

    // ---- fused ypred: out[i][row0+row] = sum_j Wy[i][j] * h[row][j] ----
    float p[YD][4] = {};
    if (lg < 2) {
#pragma unroll
        for (int nf = 0; nf < 8; ++nf) {
            const int col = w * 128 + nf * 16 + lr;
#pragma unroll
            for (int i = 0; i < YD; ++i) {
                const float wv = Wy[(size_t)i * KD + col];
#pragma unroll
                for (int r = 0; r < 4; ++r)
                    p[i][r] = fmaf(wv, (float)hreg[nf][r], p[i][r]);
            }
        }
    }
#pragma unroll
    for (int i = 0; i < YD; ++i)
#pragma unroll
        for (int r = 0; r < 4; ++r) {
            p[i][r] += __shfl_xor(p[i][r], 1);
            p[i][r] += __shfl_xor(p[i][r], 2);
            p[i][r] += __shfl_xor(p[i][r], 4);
            p[i][r] += __shfl_xor(p[i][r], 8);
        }
    float* pp = (float*)lds;         // slab dead; [8 waves][YD*8] partials
    if (lg < 2 && lr == 0) {
#pragma unroll
        for (int i = 0; i < YD; ++i)
#pragma unroll
            for (int r = 0; r < 4; ++r)
                pp[w * 80 + i * 8 + myrow + r] = p[i][r];
    }
    __syncthreads();
    if (t < 80) {
        float s = 0.f;
#pragma unroll
        for (int w2 = 0; w2 < 8; ++w2) s += pp[w2 * 80 + t];
        out[(size_t)(t >> 3) * BATCH + row0 + (t & 7)] = s;
    }
}

// ---------------------------------------------------------------------------
// Power iteration (deterministic, no atomics): wout = WtW @ (win/||win||)
// ---------------------------------------------------------------------------
__global__ __launch_bounds__(256) void matvec_n_kernel(const float* __restrict__ WtW,
                                                       const float* __restrict__ win,
                                                       float* __restrict__ wout)
{
    __shared__ float red[4];
    __shared__ float invnS;
    const int t = threadIdx.x;
    const int wave = t >> 6, lane = t & 63;

    const float4 wv = *(const float4*)(win + t * 4);
    float ss = wv.x * wv.x + wv.y * wv.y + wv.z * wv.z + wv.w * wv.w;
#pragma unroll
    for (int off = 32; off > 0; off >>= 1) ss += __shfl_down(ss, off);
    if (lane == 0) red[wave] = ss;
    __syncthreads();
    if (t == 0) invnS = 1.0f / (sqrtf(red[0] + red[1] + red[2] + red[3]) + 1e-12f);
    __syncthreads();
    const float invn = invnS;

    const int row = blockIdx.x * 4 + wave;
    const float* rp = WtW + (size_t)row * KD;
    float s = 0.f;
#pragma unroll
    for (int q = 0; q < KD / 64; ++q)
        s = fmaf(rp[lane + 64 * q], win[lane + 64 * q] * invn, s);
#pragma unroll
    for (int off = 32; off > 0; off >>= 1) s += __shfl_down(s, off);
    if (lane == 0) wout[row] = s;
}

__global__ __launch_bounds__(1024) void rayleigh_n_kernel(const float* __restrict__ wprev,
                                                          const float* __restrict__ wlast,
                                                          float* __restrict__ invL)
{
    __shared__ float red[16];
    __shared__ float invnS;
    const int t = threadIdx.x;
    const float a = wprev[t];
    float ss = a * a;
#pragma unroll
    for (int off = 32; off > 0; off >>= 1) ss += __shfl_down(ss, off);
    if ((t & 63) == 0) red[t >> 6] = ss;
    __syncthreads();
    if (t < 64) {
        float v = (t < 16) ? red[t] : 0.f;
#pragma unroll
        for (int off = 8; off > 0; off >>= 1) v += __shfl_down(v, off);
        if (t == 0) invnS = 1.0f / (sqrtf(v) + 1e-12f);
    }
    __syncthreads();
    float s = (a * invnS) * wlast[t];
#pragma unroll
    for (int off = 32; off > 0; off >>= 1) s += __shfl_down(s, off);
    __syncthreads();
    if ((t & 63) == 0) red[t >> 6] = s;
    __syncthreads();
    if (t == 0) {
        float tot = 0.f;
#pragma unroll
        for (int i = 0; i < 16; ++i) tot += red[i];
        invL[0] = 1.0f / tot;
    }
}

// ---------------------------------------------------------------------------
extern "C" void kernel_launch(void* const* d_in, const int* in_sizes, int n_in,
                              void* d_out, int out_size, void* d_ws, size_t ws_size,
                              hipStream_t stream)
{
    const float* x      = (const float*)d_in[0];   // [784 x 2048]
    const float* Wx     = (const float*)d_in[1];   // [784 x 1024]
    const float* Wy     = (const float*)d_in[2];   // [10 x 1024]
    const float* h_init = (const float*)d_in[3];   // [2048 x 1024]
    float* out = (float*)d_out;                    // [10 x 2048]

    char* base = (char*)d_ws;
    const size_t MB = 1 << 20;
    float* WtW  = (float*)(base + 0 * MB);         // 4 MB
    float* XtW  = (float*)(base + 4 * MB);         // 8 MB
    f16* bhiP   = (f16*)(base + 12 * MB);          // 2 MB
    f16* h0f    = (f16*)(base + 14 * MB);          // 4 MB
    float* wA   = (float*)(base + 18 * MB);
    float* wB   = (float*)(base + 18 * MB + 8192);
    float* invL = (float*)(base + 18 * MB + 16384);

    // 1) fused setup: WtW, XtW, h_init->f16, power-init   (one launch)
    setup_fused<<<1793, 256, 0, stream>>>(x, Wx, h_init, WtW, XtW, h0f, wA);

    // 2) bhi = f16(256*WtW)
    convert_bhi<<<512, 256, 0, stream>>>(WtW, bhiP);

    // 3) Lipschitz via power iteration (spectral gap ~2e-3: converged below
    //    fp32 eps by iter ~3; 5 matvecs). it even -> wB, odd -> wA;
    //    it=3 -> wA(u4), it=4 -> wB(u5).
    float* wcur = wA; float* wnxt = wB;
    for (int it = 0; it < 5; ++it) {
        matvec_n_kernel<<<KD / 4, 256, 0, stream>>>(WtW, wcur, wnxt);
        float* tmp = wcur; wcur = wnxt; wnxt = tmp;
    }
    rayleigh_n_kernel<<<1, 1024, 0, stream>>>(wA, wB, invL);  // (u4, u5)

    // 4+5) ALL 60 FISTA iterations + ypred: ONE normal launch
    //      (blocks fully independent: rows don't couple)
    fista_rows<<<256, 512, 0, stream>>>(h0f, bhiP, XtW, invL, Wy, out);
}

// Round 18
// 1294.197 us; speedup vs baseline: 6.4942x; 6.4942x over previous
//
#include <hip/hip_runtime.h>
#include <math.h>

#define KD    1024   // k
#define BATCH 2048
#define XD    784
#define YD    10

typedef _Float16 f16;
typedef _Float16 f16x8 __attribute__((ext_vector_type(8)));
typedef _Float16 f16x4 __attribute__((ext_vector_type(4)));
typedef float    f32x4 __attribute__((ext_vector_type(4)));

// ---------------------------------------------------------------------------
// async global->LDS, 16B per lane: per-lane global src, wave-uniform LDS dest;
// lane l lands at dst + 16*l.
// ---------------------------------------------------------------------------
__device__ __forceinline__ void gll16(const void* g, void* l)
{
    __builtin_amdgcn_global_load_lds(
        (const __attribute__((address_space(1))) void*)g,
        (__attribute__((address_space(3))) void*)l,
        16, 0, 0);
}

// ---------------------------------------------------------------------------
// setup16 (one launch): split-f16 3-pass MFMA setup GEMMs + h convert + w0.
//   blocks [0,256):   WtW = Wx^T Wx  -> bhi = f16(256*WtW), WtW fp32
//   blocks [256,768): XtW = x^T Wx   -> xth/xtl f16 hi/lo   (no fp32 XtW)
//   blocks [768,1792): h_init -> f16
//   block 1792: power-iteration init vector
// GEMM: 64x64 tile, 4 waves (2x2, wave 32x32), K=784 in 25 k-tiles of 32.
// Inputs pre-scaled x256 on split (lo-planes stay f16-normal); output scales
// are exact powers of two (acc = 65536 * A^T B).
// Error: ~1.5e-6 rel (3-pass hi/lo, positive data, no cancellation).
// ---------------------------------------------------------------------------
#define SST 80   // LDS row stride bytes (40 f16: 32 k + pad) -> 16B aligned

__global__ __launch_bounds__(256) void setup16(const float* __restrict__ x,
                                               const float* __restrict__ Wx,
                                               const float* __restrict__ h_init,
                                               float* __restrict__ WtW,
                                               f16* __restrict__ bhi,
                                               f16* __restrict__ xth,
                                               f16* __restrict__ xtl,
                                               f16* __restrict__ h0f,
                                               float* __restrict__ w0)
{
    const int blk = blockIdx.x;
    const int t   = threadIdx.x;

    if (blk >= 1792) {                       // power-init vector
        ((float4*)w0)[t] = make_float4(0.03125f, 0.03125f, 0.03125f, 0.03125f);
        return;
    }
    if (blk >= 768) {                        // h_init -> f16 (x8)
        const int i = (blk - 768) * 256 + t;
        const f32x4 a = ((const f32x4*)h_init)[2 * i];
        const f32x4 b = ((const f32x4*)h_init)[2 * i + 1];
        f16x8 o;
#pragma unroll
        for (int j = 0; j < 4; ++j) { o[j] = (f16)a[j]; o[j + 4] = (f16)b[j]; }
        ((f16x8*)h0f)[i] = o;
        return;
    }

    // ---- GEMM jobs ----
    const bool isW = (blk < 256);
    const float* A; const float* B; int M, N, i0, j0;
    if (isW) { A = Wx; B = Wx; M = KD;    N = KD; i0 = (blk >> 4) * 64;         j0 = (blk & 15) * 64; }
    else     { A = x;  B = Wx; M = BATCH; N = KD; i0 = ((blk - 256) >> 4) * 64; j0 = ((blk - 256) & 15) * 64; }

    __shared__ char sm[4 * 64 * SST];        // Ah | Al | Bh | Bl, 20 KiB
    char* Ah = sm;
    char* Al = sm + 64 * SST;
    char* Bh = sm + 2 * 64 * SST;
    char* Bl = sm + 3 * 64 * SST;

    const int lane = t & 63, wid = t >> 6;
    const int wm = wid >> 1, wn = wid & 1;
    const int lg = lane >> 4, lr = lane & 15;

    // staging decode: t<128 stages A, t>=128 stages B. 128 thr = 8 k-quads x 16 cols.
    const bool doB = (t >= 128);
    const int tt  = t & 127;
    const int su  = tt >> 4;                 // k-quad 0..7
    const int sc4 = (tt & 15) * 4;           // col 0..60
    const float* src = doB ? B : A;
    const int sw     = doB ? N : M;
    const int sbase  = doB ? j0 : i0;
    char* dsth = doB ? Bh : Ah;
    char* dstl = doB ? Bl : Al;

    f32x4 acc[2][2] = {};

#pragma unroll 1
    for (int k0 = 0; k0 < 800; k0 += 32) {   // 25 k-tiles (tail zero-padded)
        float4 r[4];
#pragma unroll
        for (int dk = 0; dk < 4; ++dk) {
            const int k = k0 + 4 * su + dk;
            r[dk] = (k < XD) ? *(const float4*)(src + (size_t)k * sw + sbase + sc4)
                             : make_float4(0.f, 0.f, 0.f, 0.f);
        }
        __syncthreads();                     // previous tile's frag reads done
#pragma unroll
        for (int j2 = 0; j2 < 4; ++j2) {     // 4x4 in-register transpose
            const int c = sc4 + j2;
            f16x4 h4, l4;
#pragma unroll
            for (int dk = 0; dk < 4; ++dk) {
                const float v = ((const float*)&r[dk])[j2] * 256.0f;
                const f16 hi = (f16)v;
                const f16 lo = (f16)(v - (float)hi);
                h4[dk] = hi;
                l4[dk] = lo;
            }
            *(f16x4*)(dsth + c * SST + su * 8) = h4;
            *(f16x4*)(dstl + c * SST + su * 8) = l4;
        }
        __syncthreads();

        f16x8 Afh[2], Afl[2], Bfh[2], Bfl[2];
#pragma unroll
        for (int f = 0; f < 2; ++f) {
            const int m = wm * 32 + f * 16 + lr;
            Afh[f] = *(const f16x8*)(Ah + m * SST + 16 * lg);
            Afl[f] = *(const f16x8*)(Al + m * SST + 16 * lg);
        }
#pragma unroll
        for (int b = 0; b < 2; ++b) {
            const int c = wn * 32 + b * 16 + lr;
            Bfh[b] = *(const f16x8*)(Bh + c * SST + 16 * lg);
            Bfl[b] = *(const f16x8*)(Bl + c * SST + 16 * lg);
        }
        // 3-pass split MFMA: Al*Bh + Ah*Bl + Ah*Bh
#pragma unroll
        for (int f = 0; f < 2; ++f)
#pragma unroll
            for (int b = 0; b < 2; ++b)
                acc[f][b] = __builtin_amdgcn_mfma_f32_16x16x32_f16(Afl[f], Bfh[b], acc[f][b], 0, 0, 0);
#pragma unroll
        for (int f = 0; f < 2; ++f)
#pragma unroll
            for (int b = 0; b < 2; ++b)
                acc[f][b] = __builtin_amdgcn_mfma_f32_16x16x32_f16(Afh[f], Bfl[b], acc[f][b], 0, 0, 0);
#pragma unroll
        for (int f = 0; f < 2; ++f)
#pragma unroll
            for (int b = 0; b < 2; ++b)
                acc[f][b] = __builtin_amdgcn_mfma_f32_16x16x32_f16(Afh[f], Bfh[b], acc[f][b], 0, 0, 0);
    }

    // ---- epilogue: acc = 65536 * C. WtW job -> bhi=f16(acc/256), WtW=acc/65536;
    //      XtW job -> xth/xtl = split(acc/65536). Coalesced 2B/4B stores (lr-major).
#pragma unroll
    for (int f = 0; f < 2; ++f)
#pragma unroll
        for (int b = 0; b < 2; ++b)
#pragma unroll
            for (int r2 = 0; r2 < 4; ++r2) {
                const int row = i0 + wm * 32 + 16 * f + 4 * lg + r2;
                const int col = j0 + wn * 32 + 16 * b + lr;
                const float av = acc[f][b][r2];
                if (isW) {
                    bhi[(size_t)row * KD + col] = (f16)(av * 0.00390625f);     // f16(256*WtW)
                    WtW[(size_t)row * KD + col] = av * 1.52587890625e-05f;     // /65536
                } else {
                    const float sv = av * 1.52587890625e-05f;                  // XtW
                    const f16 hi = (f16)sv;
                    const f16 lo = (f16)(sv - (float)hi);
                    xth[(size_t)row * KD + col] = hi;
                    xtl[(size_t)row * KD + col] = lo;
                }
            }
}

// ---------------------------------------------------------------------------
// Fused FISTA step, single-pass f16 MFMA, B FULLY RESIDENT in LDS (160 KiB).
// UNCHANGED from round 13 (proven: absmax 0.00390625, ~19.5 us/dispatch).
// ---------------------------------------------------------------------------
#define BMF 128
#define BNF 64
#define A_OFF 131072   // A buffers start after the 128 KiB B region

__global__ __launch_bounds__(512, 1) void fista160(
    const f16* __restrict__ yhP,   // A operand + epilogue y  [BATCH][KD]
    const f16* __restrict__ hhP,   // epilogue h              [BATCH][KD]
    const f16* __restrict__ bhiP,  // f16(256*WtW)            [KD][KD]
    const f16* __restrict__ xthP,  // XtW hi plane (f16)      [BATCH][KD]
    const f16* __restrict__ xtlP,  // XtW lo plane (f16)
    const float* __restrict__ invLp, float cm,
    f16* __restrict__ HO, f16* __restrict__ YO)
{
    __shared__ char lds[163840];   // 160 KiB: [0,128K) B, [128K,160K) A dbuf

    const int t    = threadIdx.x;
    const int lane = t & 63;
    const int wid  = t >> 6;       // 0..7
    const int wm   = wid >> 1;     // 0..3 (32-row block)
    const int wn   = wid & 1;      // 0..1 (32-col block)
    const int lr   = lane & 15;
    const int lk   = (lane >> 4) * 8;

    // XCD swizzle: region 4m x 8n per XCD (~3MB working set < 4MB L2)
    const int bid = blockIdx.y * gridDim.x + blockIdx.x;   // 0..255
    const int xc  = bid & 7, j = bid >> 3;                 // j: 0..31
    const int m0  = ((xc >> 1) * 4 + (j >> 3)) * BMF;      // 16 m-tiles
    const int n0  = ((xc & 1) * 8 + (j & 7)) * BNF;        // 16 n-tiles

    // ---- B prologue stage: 128 chunks of 1 KiB (16 per wave) ----
#pragma unroll
    for (int i = 0; i < 16; ++i) {
        const int c = wid * 16 + i;
        const int kt = c >> 3, u = c & 7;
        const int g = u & 3, s = u >> 2;
        gll16(bhiP + (size_t)(n0 + 16 * g + lr) * KD + kt * 64 + s * 32 + lk,
              lds + c * 1024 + lane * 16);
    }

    // ---- A staging: 16 chunks/kt (2 per wave) ----
    auto stageA = [&](int buf, int kt) {
#pragma unroll
        for (int i = 0; i < 2; ++i) {
            const int a = wid * 2 + i;
            const int g = a & 7, s = a >> 3;
            gll16(yhP + (size_t)(m0 + 16 * g + lr) * KD + kt * 64 + 32 * s + lk,
                  lds + A_OFF + buf * 16384 + a * 1024 + lane * 16);
        }
    };

    stageA(0, 0);
    asm volatile("s_waitcnt vmcnt(0)" ::: "memory");   // B panel + A kt0 landed
    __builtin_amdgcn_s_barrier();
    asm volatile("" ::: "memory");

    f32x4 acc[2][2] = {};

#pragma unroll
    for (int kt = 0; kt < 16; ++kt) {
        const int buf = kt & 1;
        if (kt < 15) stageA(buf ^ 1, kt + 1);

        f16x8 Af[2][2], Bf[2][2];
#pragma unroll
        for (int s = 0; s < 2; ++s) {
#pragma unroll
            for (int f = 0; f < 2; ++f)
                Af[s][f] = *(const f16x8*)(lds + A_OFF + buf * 16384
                                           + ((s << 3) + wm * 2 + f) * 1024 + lane * 16);
#pragma unroll
            for (int b = 0; b < 2; ++b)
                Bf[s][b] = *(const f16x8*)(lds + (kt * 8 + (s << 2) + wn * 2 + b) * 1024
                                           + lane * 16);
        }
#pragma unroll
        for (int s = 0; s < 2; ++s)
#pragma unroll
            for (int f = 0; f < 2; ++f)
#pragma unroll
                for (int b = 0; b < 2; ++b)
                    acc[f][b] = __builtin_amdgcn_mfma_f32_16x16x32_f16(Af[s][f], Bf[s][b], acc[f][b], 0, 0, 0);

        if (kt < 15) { asm volatile("s_waitcnt vmcnt(0)" ::: "memory"); }
        __builtin_amdgcn_s_barrier();
        asm volatile("" ::: "memory");
    }

    // ---- epilogue: acc -> LDS fp32 [128][68] at lds base (B region dead) ----
    float* eb = (float*)lds;
#pragma unroll
    for (int f = 0; f < 2; ++f)
#pragma unroll
        for (int b = 0; b < 2; ++b) {
            const int r0 = wm * 32 + 16 * f + 4 * (lane >> 4);
            const int cl = wn * 32 + 16 * b + lr;
#pragma unroll
            for (int r = 0; r < 4; ++r)
                eb[(r0 + r) * 68 + cl] = acc[f][b][r];
        }
    __syncthreads();

    const int row = t >> 2;            // 0..127
    const int cb  = (t & 3) * 16;      // 0,16,32,48
    const float invL  = invLp[0];
    const float invLs = invL * 0.00390625f;   // invL/256 (fold WtW scale)
    const size_t gb = (size_t)(m0 + row) * KD + n0 + cb;
    {
        const f32x4 a0 = *(const f32x4*)(eb + row * 68 + cb);
        const f32x4 a1 = *(const f32x4*)(eb + row * 68 + cb + 4);
        const f32x4 a2 = *(const f32x4*)(eb + row * 68 + cb + 8);
        const f32x4 a3 = *(const f32x4*)(eb + row * 68 + cb + 12);
        const f16x8 yh8a = *(const f16x8*)(yhP + gb);
        const f16x8 yh8b = *(const f16x8*)(yhP + gb + 8);
        const f16x8 hh8a = *(const f16x8*)(hhP + gb);
        const f16x8 hh8b = *(const f16x8*)(hhP + gb + 8);
        const f16x8 xh8a = *(const f16x8*)(xthP + gb);
        const f16x8 xh8b = *(const f16x8*)(xthP + gb + 8);
        const f16x8 xl8a = *(const f16x8*)(xtlP + gb);
        const f16x8 xl8b = *(const f16x8*)(xtlP + gb + 8);
        f16x8 oha, ohb, oya, oyb;
#pragma unroll
        for (int jj = 0; jj < 8; ++jj) {
            const float av = (jj < 4) ? a0[jj] : a1[jj - 4];
            const float xv = (float)xh8a[jj] + (float)xl8a[jj];
            const float yv = (float)yh8a[jj];
            const float hv = (float)hh8a[jj];
            const float t1 = fmaf(invL, xv, yv);
            const float hn = fmaxf(fmaf(-invLs, av, t1), 0.f);
            const float yn = fmaf(cm, hn - hv, hn);
            oha[jj] = (f16)hn;
            oya[jj] = (f16)yn;
        }
#pragma unroll
        for (int jj = 0; jj < 8; ++jj) {
            const float av = (jj < 4) ? a2[jj] : a3[jj - 4];
            const float xv = (float)xh8b[jj] + (float)xl8b[jj];
            const float yv = (float)yh8b[jj];
            const float hv = (float)hh8b[jj];
            const float t1 = fmaf(invL, xv, yv);
            const float hn = fmaxf(fmaf(-invLs, av, t1), 0.f);
            const float yn = fmaf(cm, hn - hv, hn);
            ohb[jj] = (f16)hn;
            oyb[jj] = (f16)yn;
        }
        *(f16x8*)(HO + gb)     = oha;
        *(f16x8*)(HO + gb + 8) = ohb;
        *(f16x8*)(YO + gb)     = oya;
        *(f16x8*)(YO + gb + 8) = oyb;
    }
}

// ---------------------------------------------------------------------------
// Power iteration (deterministic, no atomics): wout = WtW @ (win/||win||)
// ---------------------------------------------------------------------------
__global__ __launch_bounds__(256) void matvec_n_kernel(const float* __restrict__ WtW,
                                                       const float* __restrict__ win,
                                                       float* __restrict__ wout)
{
    __shared__ float red[4];
    __shared__ float invnS;
    const int t = threadIdx.x;
    const int wave = t >> 6, lane = t & 63;

    const float4 wv = *(const float4*)(win + t * 4);
    float ss = wv.x * wv.x + wv.y * wv.y + wv.z * wv.z + wv.w * wv.w;
#pragma unroll
    for (int off = 32; off > 0; off >>= 1) ss += __shfl_down(ss, off);
    if (lane == 0) red[wave] = ss;
    __syncthreads();
    if (t == 0) invnS = 1.0f / (sqrtf(red[0] + red[1] + red[2] + red[3]) + 1e-12f);
    __syncthreads();
    const float invn = invnS;

    const int row = blockIdx.x * 4 + wave;
    const float* rp = WtW + (size_t)row * KD;
    float s = 0.f;
#pragma unroll
    for (int q = 0; q < KD / 64; ++q)
        s = fmaf(rp[lane + 64 * q], win[lane + 64 * q] * invn, s);
#pragma unroll
    for (int off = 32; off > 0; off >>= 1) s += __shfl_down(s, off);
    if (lane == 0) wout[row] = s;
}

__global__ __launch_bounds__(1024) void rayleigh_n_kernel(const float* __restrict__ wprev,
                                                          const float* __restrict__ wlast,
                                                          float* __restrict__ invL)
{
    __shared__ float red[16];
    __shared__ float invnS;
    const int t = threadIdx.x;
    const float a = wprev[t];
    float ss = a * a;
#pragma unroll
    for (int off = 32; off > 0; off >>= 1) ss += __shfl_down(ss, off);
    if ((t & 63) == 0) red[t >> 6] = ss;
    __syncthreads();
    if (t < 64) {
        float v = (t < 16) ? red[t] : 0.f;
#pragma unroll
        for (int off = 8; off > 0; off >>= 1) v += __shfl_down(v, off);
        if (t == 0) invnS = 1.0f / (sqrtf(v) + 1e-12f);
    }
    __syncthreads();
    float s = (a * invnS) * wlast[t];
#pragma unroll
    for (int off = 32; off > 0; off >>= 1) s += __shfl_down(s, off);
    __syncthreads();
    if ((t & 63) == 0) red[t >> 6] = s;
    __syncthreads();
    if (t == 0) {
        float tot = 0.f;
#pragma unroll
        for (int i = 0; i < 16; ++i) tot += red[i];
        invL[0] = 1.0f / tot;
    }
}

// ---------------------------------------------------------------------------
// out[i][b] = sum_j Wy[i][j] * H[b][j]   (out: [YD x BATCH])
// ---------------------------------------------------------------------------
__global__ __launch_bounds__(256) void ypred_kernel(const float* __restrict__ Wy,
                                                    const f16* __restrict__ hh,
                                                    float* __restrict__ out)
{
    const int wave = threadIdx.x >> 6;
    const int lane = threadIdx.x & 63;
    const int b    = blockIdx.x * 4 + wave;
    float p[YD] = {};
    const f16* hp = hh + (size_t)b * KD;
#pragma unroll 4
    for (int q = 0; q < KD / 64; ++q) {
        const int j = lane + 64 * q;
        const float hv = (float)hp[j];
#pragma unroll
        for (int i = 0; i < YD; ++i)
            p[i] = fmaf(Wy[i * KD + j], hv, p[i]);
    }
#pragma unroll
    for (int i = 0; i < YD; ++i) {
        float s = p[i];
#pragma unroll
        for (int off = 32; off > 0; off >>= 1)
            s += __shfl_down(s, off);
        if (lane == 0) out[(size_t)i * BATCH + b] = s;
    }
}

// ---------------------------------------------------------------------------
extern "C" void kernel_launch(void* const* d_in, const int* in_sizes, int n_in,
                              void* d_out, int out_size, void* d_ws, size_t ws_size,
                              hipStream_t stream)
{
    const float* x      = (const float*)d_in[0];   // [784 x 2048]
    const float* Wx     = (const float*)d_in[1];   // [784 x 1024]
    const float* Wy     = (const float*)d_in[2];   // [10 x 1024]
    const float* h_init = (const float*)d_in[3];   // [2048 x 1024]
    float* out = (float*)d_out;                    // [10 x 2048]

    char* base = (char*)d_ws;
    const size_t MB = 1 << 20;
    float* WtW  = (float*)(base + 0 * MB);         // 4 MB (power iteration)
    f16* bhiP   = (f16*)(base + 4 * MB);           // 2 MB
    f16* xthP   = (f16*)(base + 6 * MB);           // 4 MB
    f16* xtlP   = (f16*)(base + 10 * MB);          // 4 MB
    f16* h0f    = (f16*)(base + 14 * MB);          // 4 MB
    f16* hA     = (f16*)(base + 18 * MB);
    f16* yA     = (f16*)(base + 22 * MB);
    f16* hB     = (f16*)(base + 26 * MB);
    f16* yB     = (f16*)(base + 30 * MB);
    float* wA   = (float*)(base + 34 * MB);
    float* wB   = (float*)(base + 34 * MB + 8192);
    float* invL = (float*)(base + 34 * MB + 16384);

    // 1) fused MFMA setup: bhi/WtW, xth/xtl, h_init->f16, power-init (one launch;
    //    convert pass eliminated -- GEMM epilogues emit f16 planes directly)
    setup16<<<1793, 256, 0, stream>>>(x, Wx, h_init, WtW, bhiP, xthP, xtlP, h0f, wA);

    // 2) Lipschitz via power iteration (5 matvecs validated in rounds 12-13).
    //    writes: it even -> wB, odd -> wA; it=3 -> wA(u4), it=4 -> wB(u5).
    float* wcur = wA; float* wnxt = wB;
    for (int it = 0; it < 5; ++it) {
        matvec_n_kernel<<<KD / 4, 256, 0, stream>>>(WtW, wcur, wnxt);
        float* tmp = wcur; wcur = wnxt; wnxt = tmp;
    }
    rayleigh_n_kernel<<<1, 1024, 0, stream>>>(wA, wB, invL);  // (u4, u5)

    // 3) 60 FISTA iterations (t restarts at iter 50: y = h, t = 1)
    float t = 1.0f;
    const f16 *yin = h0f, *hin = h0f;
    int outSel = 1;                                 // 1 -> A set, 0 -> B set
    for (int n = 0; n < 60; ++n) {
        if (n == 50) { t = 1.0f; yin = hin; }
        const float tn = 0.5f * (1.0f + sqrtf(1.0f + 4.0f * t * t));
        const float cm = (t - 1.0f) / tn;
        f16* ho = outSel ? hA : hB;
        f16* yo = outSel ? yA : yB;
        fista160<<<dim3(KD / BNF, BATCH / BMF), 512, 0, stream>>>(
            yin, hin, bhiP, xthP, xtlP, invL, cm, ho, yo);
        t = tn;
        hin = ho; yin = yo;
        outSel ^= 1;
    }

    // 4) out = Wy @ h^T
    ypred_kernel<<<BATCH / 4, 256, 0, stream>>>(Wy, hin, out);
}

// Round 19
// 1275.154 us; speedup vs baseline: 6.5912x; 1.0149x over previous
//
#include <hip/hip_runtime.h>
#include <math.h>

#define KD    1024   // k
#define BATCH 2048
#define XD    784
#define YD    10

typedef _Float16 f16;
typedef _Float16 f16x8 __attribute__((ext_vector_type(8)));
typedef _Float16 f16x4 __attribute__((ext_vector_type(4)));
typedef float    f32x4 __attribute__((ext_vector_type(4)));

// ---------------------------------------------------------------------------
// async global->LDS, 16B per lane: per-lane global src, wave-uniform LDS dest;
// lane l lands at dst + 16*l.
// ---------------------------------------------------------------------------
__device__ __forceinline__ void gll16(const void* g, void* l)
{
    __builtin_amdgcn_global_load_lds(
        (const __attribute__((address_space(1))) void*)g,
        (__attribute__((address_space(3))) void*)l,
        16, 0, 0);
}

// ---------------------------------------------------------------------------
// setup16 (one launch): split-f16 3-pass MFMA setup GEMMs + h convert + w0.
//   blocks [0,256):   WtW = Wx^T Wx  -> bhi = f16(256*WtW), WtW fp32
//   blocks [256,768): XtW = x^T Wx   -> xth/xtl f16 hi/lo
//   blocks [768,1792): h_init -> f16
//   block 1792: power-iteration init vector
// GEMM: 64x64 tile, 4 waves (2x2, wave 32x32), K=784 in 25 k-tiles of 32.
// STAGING DECODE FIX vs round 18: su = tt&7, colq = tt>>3. A 16-lane group
// now writes banks {2su(+1)} x {c4=0,1 -> +16} = all 32 banks exactly once
// -> transpose ds_writes conflict-free (was 8-way: col-stride-4 groups hit
// 2 banks). Same (c,su)->data mapping => LDS contents and outputs are
// BIT-IDENTICAL to round 18.
// ---------------------------------------------------------------------------
#define SST 80   // LDS row stride bytes (40 f16: 32 k + pad) -> 16B aligned

__global__ __launch_bounds__(256) void setup16(const float* __restrict__ x,
                                               const float* __restrict__ Wx,
                                               const float* __restrict__ h_init,
                                               float* __restrict__ WtW,
                                               f16* __restrict__ bhi,
                                               f16* __restrict__ xth,
                                               f16* __restrict__ xtl,
                                               f16* __restrict__ h0f,
                                               float* __restrict__ w0)
{
    const int blk = blockIdx.x;
    const int t   = threadIdx.x;

    if (blk >= 1792) {                       // power-init vector
        ((float4*)w0)[t] = make_float4(0.03125f, 0.03125f, 0.03125f, 0.03125f);
        return;
    }
    if (blk >= 768) {                        // h_init -> f16 (x8)
        const int i = (blk - 768) * 256 + t;
        const f32x4 a = ((const f32x4*)h_init)[2 * i];
        const f32x4 b = ((const f32x4*)h_init)[2 * i + 1];
        f16x8 o;
#pragma unroll
        for (int j = 0; j < 4; ++j) { o[j] = (f16)a[j]; o[j + 4] = (f16)b[j]; }
        ((f16x8*)h0f)[i] = o;
        return;
    }

    // ---- GEMM jobs ----
    const bool isW = (blk < 256);
    const float* A; const float* B; int M, N, i0, j0;
    if (isW) { A = Wx; B = Wx; M = KD;    N = KD; i0 = (blk >> 4) * 64;         j0 = (blk & 15) * 64; }
    else     { A = x;  B = Wx; M = BATCH; N = KD; i0 = ((blk - 256) >> 4) * 64; j0 = ((blk - 256) & 15) * 64; }

    __shared__ char sm[4 * 64 * SST];        // Ah | Al | Bh | Bl, 20 KiB
    char* Ah = sm;
    char* Al = sm + 64 * SST;
    char* Bh = sm + 2 * 64 * SST;
    char* Bl = sm + 3 * 64 * SST;

    const int lane = t & 63, wid = t >> 6;
    const int wm = wid >> 1, wn = wid & 1;
    const int lg = lane >> 4, lr = lane & 15;

    // staging decode: t<128 stages A, t>=128 stages B.
    // 128 thr = 8 k-quads (su = tt&7) x 16 col-quads (tt>>3).
    const bool doB = (t >= 128);
    const int tt  = t & 127;
    const int su  = tt & 7;                  // k-quad 0..7   (conflict-free fix)
    const int sc4 = (tt >> 3) * 4;           // col 0..60
    const float* src = doB ? B : A;
    const int sw     = doB ? N : M;
    const int sbase  = doB ? j0 : i0;
    char* dsth = doB ? Bh : Ah;
    char* dstl = doB ? Bl : Al;

    f32x4 acc[2][2] = {};

#pragma unroll 1
    for (int k0 = 0; k0 < 800; k0 += 32) {   // 25 k-tiles (tail zero-padded)
        float4 r[4];
#pragma unroll
        for (int dk = 0; dk < 4; ++dk) {
            const int k = k0 + 4 * su + dk;
            r[dk] = (k < XD) ? *(const float4*)(src + (size_t)k * sw + sbase + sc4)
                             : make_float4(0.f, 0.f, 0.f, 0.f);
        }
        __syncthreads();                     // previous tile's frag reads done
#pragma unroll
        for (int j2 = 0; j2 < 4; ++j2) {     // 4x4 in-register transpose
            const int c = sc4 + j2;
            f16x4 h4, l4;
#pragma unroll
            for (int dk = 0; dk < 4; ++dk) {
                const float v = ((const float*)&r[dk])[j2] * 256.0f;
                const f16 hi = (f16)v;
                const f16 lo = (f16)(v - (float)hi);
                h4[dk] = hi;
                l4[dk] = lo;
            }
            *(f16x4*)(dsth + c * SST + su * 8) = h4;
            *(f16x4*)(dstl + c * SST + su * 8) = l4;
        }
        __syncthreads();

        f16x8 Afh[2], Afl[2], Bfh[2], Bfl[2];
#pragma unroll
        for (int f = 0; f < 2; ++f) {
            const int m = wm * 32 + f * 16 + lr;
            Afh[f] = *(const f16x8*)(Ah + m * SST + 16 * lg);
            Afl[f] = *(const f16x8*)(Al + m * SST + 16 * lg);
        }
#pragma unroll
        for (int b = 0; b < 2; ++b) {
            const int c = wn * 32 + b * 16 + lr;
            Bfh[b] = *(const f16x8*)(Bh + c * SST + 16 * lg);
            Bfl[b] = *(const f16x8*)(Bl + c * SST + 16 * lg);
        }
        // 3-pass split MFMA: Al*Bh + Ah*Bl + Ah*Bh
#pragma unroll
        for (int f = 0; f < 2; ++f)
#pragma unroll
            for (int b = 0; b < 2; ++b)
                acc[f][b] = __builtin_amdgcn_mfma_f32_16x16x32_f16(Afl[f], Bfh[b], acc[f][b], 0, 0, 0);
#pragma unroll
        for (int f = 0; f < 2; ++f)
#pragma unroll
            for (int b = 0; b < 2; ++b)
                acc[f][b] = __builtin_amdgcn_mfma_f32_16x16x32_f16(Afh[f], Bfl[b], acc[f][b], 0, 0, 0);
#pragma unroll
        for (int f = 0; f < 2; ++f)
#pragma unroll
            for (int b = 0; b < 2; ++b)
                acc[f][b] = __builtin_amdgcn_mfma_f32_16x16x32_f16(Afh[f], Bfh[b], acc[f][b], 0, 0, 0);
    }

    // ---- epilogue: acc = 65536 * C. WtW job -> bhi=f16(acc/256), WtW=acc/65536;
    //      XtW job -> xth/xtl = split(acc/65536). Coalesced 2B/4B stores (lr-major).
#pragma unroll
    for (int f = 0; f < 2; ++f)
#pragma unroll
        for (int b = 0; b < 2; ++b)
#pragma unroll
            for (int r2 = 0; r2 < 4; ++r2) {
                const int row = i0 + wm * 32 + 16 * f + 4 * lg + r2;
                const int col = j0 + wn * 32 + 16 * b + lr;
                const float av = acc[f][b][r2];
                if (isW) {
                    bhi[(size_t)row * KD + col] = (f16)(av * 0.00390625f);     // f16(256*WtW)
                    WtW[(size_t)row * KD + col] = av * 1.52587890625e-05f;     // /65536
                } else {
                    const float sv = av * 1.52587890625e-05f;                  // XtW
                    const f16 hi = (f16)sv;
                    const f16 lo = (f16)(sv - (float)hi);
                    xth[(size_t)row * KD + col] = hi;
                    xtl[(size_t)row * KD + col] = lo;
                }
            }
}

// ---------------------------------------------------------------------------
// Fused FISTA step, single-pass f16 MFMA, B FULLY RESIDENT in LDS (160 KiB).
// UNCHANGED from round 13/18 (proven: absmax 0.00390625, ~19.5 us/dispatch).
// ---------------------------------------------------------------------------
#define BMF 128
#define BNF 64
#define A_OFF 131072   // A buffers start after the 128 KiB B region

__global__ __launch_bounds__(512, 1) void fista160(
    const f16* __restrict__ yhP,   // A operand + epilogue y  [BATCH][KD]
    const f16* __restrict__ hhP,   // epilogue h              [BATCH][KD]
    const f16* __restrict__ bhiP,  // f16(256*WtW)            [KD][KD]
    const f16* __restrict__ xthP,  // XtW hi plane (f16)      [BATCH][KD]
    const f16* __restrict__ xtlP,  // XtW lo plane (f16)
    const float* __restrict__ invLp, float cm,
    f16* __restrict__ HO, f16* __restrict__ YO)
{
    __shared__ char lds[163840];   // 160 KiB: [0,128K) B, [128K,160K) A dbuf

    const int t    = threadIdx.x;
    const int lane = t & 63;
    const int wid  = t >> 6;       // 0..7
    const int wm   = wid >> 1;     // 0..3 (32-row block)
    const int wn   = wid & 1;      // 0..1 (32-col block)
    const int lr   = lane & 15;
    const int lk   = (lane >> 4) * 8;

    // XCD swizzle: region 4m x 8n per XCD (~3MB working set < 4MB L2)
    const int bid = blockIdx.y * gridDim.x + blockIdx.x;   // 0..255
    const int xc  = bid & 7, j = bid >> 3;                 // j: 0..31
    const int m0  = ((xc >> 1) * 4 + (j >> 3)) * BMF;      // 16 m-tiles
    const int n0  = ((xc & 1) * 8 + (j & 7)) * BNF;        // 16 n-tiles

    // ---- B prologue stage: 128 chunks of 1 KiB (16 per wave) ----
#pragma unroll
    for (int i = 0; i < 16; ++i) {
        const int c = wid * 16 + i;
        const int kt = c >> 3, u = c & 7;
        const int g = u & 3, s = u >> 2;
        gll16(bhiP + (size_t)(n0 + 16 * g + lr) * KD + kt * 64 + s * 32 + lk,
              lds + c * 1024 + lane * 16);
    }

    // ---- A staging: 16 chunks/kt (2 per wave) ----
    auto stageA = [&](int buf, int kt) {
#pragma unroll
        for (int i = 0; i < 2; ++i) {
            const int a = wid * 2 + i;
            const int g = a & 7, s = a >> 3;
            gll16(yhP + (size_t)(m0 + 16 * g + lr) * KD + kt * 64 + 32 * s + lk,
                  lds + A_OFF + buf * 16384 + a * 1024 + lane * 16);
        }
    };

    stageA(0, 0);
    asm volatile("s_waitcnt vmcnt(0)" ::: "memory");   // B panel + A kt0 landed
    __builtin_amdgcn_s_barrier();
    asm volatile("" ::: "memory");

    f32x4 acc[2][2] = {};

#pragma unroll
    for (int kt = 0; kt < 16; ++kt) {
        const int buf = kt & 1;
        if (kt < 15) stageA(buf ^ 1, kt + 1);

        f16x8 Af[2][2], Bf[2][2];
#pragma unroll
        for (int s = 0; s < 2; ++s) {
#pragma unroll
            for (int f = 0; f < 2; ++f)
                Af[s][f] = *(const f16x8*)(lds + A_OFF + buf * 16384
                                           + ((s << 3) + wm * 2 + f) * 1024 + lane * 16);
#pragma unroll
            for (int b = 0; b < 2; ++b)
                Bf[s][b] = *(const f16x8*)(lds + (kt * 8 + (s << 2) + wn * 2 + b) * 1024
                                           + lane * 16);
        }
#pragma unroll
        for (int s = 0; s < 2; ++s)
#pragma unroll
            for (int f = 0; f < 2; ++f)
#pragma unroll
                for (int b = 0; b < 2; ++b)
                    acc[f][b] = __builtin_amdgcn_mfma_f32_16x16x32_f16(Af[s][f], Bf[s][b], acc[f][b], 0, 0, 0);

        if (kt < 15) { asm volatile("s_waitcnt vmcnt(0)" ::: "memory"); }
        __builtin_amdgcn_s_barrier();
        asm volatile("" ::: "memory");
    }

    // ---- epilogue: acc -> LDS fp32 [128][68] at lds base (B region dead) ----
    float* eb = (float*)lds;
#pragma unroll
    for (int f = 0; f < 2; ++f)
#pragma unroll
        for (int b = 0; b < 2; ++b) {
            const int r0 = wm * 32 + 16 * f + 4 * (lane >> 4);
            const int cl = wn * 32 + 16 * b + lr;
#pragma unroll
            for (int r = 0; r < 4; ++r)
                eb[(r0 + r) * 68 + cl] = acc[f][b][r];
        }
    __syncthreads();

    const int row = t >> 2;            // 0..127
    const int cb  = (t & 3) * 16;      // 0,16,32,48
    const float invL  = invLp[0];
    const float invLs = invL * 0.00390625f;   // invL/256 (fold WtW scale)
    const size_t gb = (size_t)(m0 + row) * KD + n0 + cb;
    {
        const f32x4 a0 = *(const f32x4*)(eb + row * 68 + cb);
        const f32x4 a1 = *(const f32x4*)(eb + row * 68 + cb + 4);
        const f32x4 a2 = *(const f32x4*)(eb + row * 68 + cb + 8);
        const f32x4 a3 = *(const f32x4*)(eb + row * 68 + cb + 12);
        const f16x8 yh8a = *(const f16x8*)(yhP + gb);
        const f16x8 yh8b = *(const f16x8*)(yhP + gb + 8);
        const f16x8 hh8a = *(const f16x8*)(hhP + gb);
        const f16x8 hh8b = *(const f16x8*)(hhP + gb + 8);
        const f16x8 xh8a = *(const f16x8*)(xthP + gb);
        const f16x8 xh8b = *(const f16x8*)(xthP + gb + 8);
        const f16x8 xl8a = *(const f16x8*)(xtlP + gb);
        const f16x8 xl8b = *(const f16x8*)(xtlP + gb + 8);
        f16x8 oha, ohb, oya, oyb;
#pragma unroll
        for (int jj = 0; jj < 8; ++jj) {
            const float av = (jj < 4) ? a0[jj] : a1[jj - 4];
            const float xv = (float)xh8a[jj] + (float)xl8a[jj];
            const float yv = (float)yh8a[jj];
            const float hv = (float)hh8a[jj];
            const float t1 = fmaf(invL, xv, yv);
            const float hn = fmaxf(fmaf(-invLs, av, t1), 0.f);
            const float yn = fmaf(cm, hn - hv, hn);
            oha[jj] = (f16)hn;
            oya[jj] = (f16)yn;
        }
#pragma unroll
        for (int jj = 0; jj < 8; ++jj) {
            const float av = (jj < 4) ? a2[jj] : a3[jj - 4];
            const float xv = (float)xh8b[jj] + (float)xl8b[jj];
            const float yv = (float)yh8b[jj];
            const float hv = (float)hh8b[jj];
            const float t1 = fmaf(invL, xv, yv);
            const float hn = fmaxf(fmaf(-invLs, av, t1), 0.f);
            const float yn = fmaf(cm, hn - hv, hn);
            ohb[jj] = (f16)hn;
            oyb[jj] = (f16)yn;
        }
        *(f16x8*)(HO + gb)     = oha;
        *(f16x8*)(HO + gb + 8) = ohb;
        *(f16x8*)(YO + gb)     = oya;
        *(f16x8*)(YO + gb + 8) = oyb;
    }
}

// ---------------------------------------------------------------------------
// Power iteration (deterministic, no atomics): wout = WtW @ (win/||win||)
// ---------------------------------------------------------------------------
__global__ __launch_bounds__(256) void matvec_n_kernel(const float* __restrict__ WtW,
                                                       const float* __restrict__ win,
                                                       float* __restrict__ wout)
{
    __shared__ float red[4];
    __shared__ float invnS;
    const int t = threadIdx.x;
    const int wave = t >> 6, lane = t & 63;

    const float4 wv = *(const float4*)(win + t * 4);
    float ss = wv.x * wv.x + wv.y * wv.y + wv.z * wv.z + wv.w * wv.w;
#pragma unroll
    for (int off = 32; off > 0; off >>= 1) ss += __shfl_down(ss, off);
    if (lane == 0) red[wave] = ss;
    __syncthreads();
    if (t == 0) invnS = 1.0f / (sqrtf(red[0] + red[1] + red[2] + red[3]) + 1e-12f);
    __syncthreads();
    const float invn = invnS;

    const int row = blockIdx.x * 4 + wave;
    const float* rp = WtW + (size_t)row * KD;
    float s = 0.f;
#pragma unroll
    for (int q = 0; q < KD / 64; ++q)
        s = fmaf(rp[lane + 64 * q], win[lane + 64 * q] * invn, s);
#pragma unroll
    for (int off = 32; off > 0; off >>= 1) s += __shfl_down(s, off);
    if (lane == 0) wout[row] = s;
}

__global__ __launch_bounds__(1024) void rayleigh_n_kernel(const float* __restrict__ wprev,
                                                          const float* __restrict__ wlast,
                                                          float* __restrict__ invL)
{
    __shared__ float red[16];
    __shared__ float invnS;
    const int t = threadIdx.x;
    const float a = wprev[t];
    float ss = a * a;
#pragma unroll
    for (int off = 32; off > 0; off >>= 1) ss += __shfl_down(ss, off);
    if ((t & 63) == 0) red[t >> 6] = ss;
    __syncthreads();
    if (t < 64) {
        float v = (t < 16) ? red[t] : 0.f;
#pragma unroll
        for (int off = 8; off > 0; off >>= 1) v += __shfl_down(v, off);
        if (t == 0) invnS = 1.0f / (sqrtf(v) + 1e-12f);
    }
    __syncthreads();
    float s = (a * invnS) * wlast[t];
#pragma unroll
    for (int off = 32; off > 0; off >>= 1) s += __shfl_down(s, off);
    __syncthreads();
    if ((t & 63) == 0) red[t >> 6] = s;
    __syncthreads();
    if (t == 0) {
        float tot = 0.f;
#pragma unroll
        for (int i = 0; i < 16; ++i) tot += red[i];
        invL[0] = 1.0f / tot;
    }
}

// ---------------------------------------------------------------------------
// out[i][b] = sum_j Wy[i][j] * H[b][j]   (out: [YD x BATCH])
// ---------------------------------------------------------------------------
__global__ __launch_bounds__(256) void ypred_kernel(const float* __restrict__ Wy,
                                                    const f16* __restrict__ hh,
                                                    float* __restrict__ out)
{
    const int wave = threadIdx.x >> 6;
    const int lane = threadIdx.x & 63;
    const int b    = blockIdx.x * 4 + wave;
    float p[YD] = {};
    const f16* hp = hh + (size_t)b * KD;
#pragma unroll 4
    for (int q = 0; q < KD / 64; ++q) {
        const int j = lane + 64 * q;
        const float hv = (float)hp[j];
#pragma unroll
        for (int i = 0; i < YD; ++i)
            p[i] = fmaf(Wy[i * KD + j], hv, p[i]);
    }
#pragma unroll
    for (int i = 0; i < YD; ++i) {
        float s = p[i];
#pragma unroll
        for (int off = 32; off > 0; off >>= 1)
            s += __shfl_down(s, off);
        if (lane == 0) out[(size_t)i * BATCH + b] = s;
    }
}

// ---------------------------------------------------------------------------
extern "C" void kernel_launch(void* const* d_in, const int* in_sizes, int n_in,
                              void* d_out, int out_size, void* d_ws, size_t ws_size,
                              hipStream_t stream)
{
    const float* x      = (const float*)d_in[0];   // [784 x 2048]
    const float* Wx     = (const float*)d_in[1];   // [784 x 1024]
    const float* Wy     = (const float*)d_in[2];   // [10 x 1024]
    const float* h_init = (const float*)d_in[3];   // [2048 x 1024]
    float* out = (float*)d_out;                    // [10 x 2048]

    char* base = (char*)d_ws;
    const size_t MB = 1 << 20;
    float* WtW  = (float*)(base + 0 * MB);         // 4 MB (power iteration)
    f16* bhiP   = (f16*)(base + 4 * MB);           // 2 MB
    f16* xthP   = (f16*)(base + 6 * MB);           // 4 MB
    f16* xtlP   = (f16*)(base + 10 * MB);          // 4 MB
    f16* h0f    = (f16*)(base + 14 * MB);          // 4 MB
    f16* hA     = (f16*)(base + 18 * MB);
    f16* yA     = (f16*)(base + 22 * MB);
    f16* hB     = (f16*)(base + 26 * MB);
    f16* yB     = (f16*)(base + 30 * MB);
    float* wA   = (float*)(base + 34 * MB);
    float* wB   = (float*)(base + 34 * MB + 8192);
    float* invL = (float*)(base + 34 * MB + 16384);

    // 1) fused MFMA setup: bhi/WtW, xth/xtl, h_init->f16, power-init (one launch)
    setup16<<<1793, 256, 0, stream>>>(x, Wx, h_init, WtW, bhiP, xthP, xtlP, h0f, wA);

    // 2) Lipschitz via power iteration (spectral gap ~2e-3: Rayleigh converged
    //    below fp32 eps by iter ~3; 4 matvecs). writes: it even -> wB, odd -> wA;
    //    it=2 -> wB(u3), it=3 -> wA(u4).
    float* wcur = wA; float* wnxt = wB;
    for (int it = 0; it < 4; ++it) {
        matvec_n_kernel<<<KD / 4, 256, 0, stream>>>(WtW, wcur, wnxt);
        float* tmp = wcur; wcur = wnxt; wnxt = tmp;
    }
    rayleigh_n_kernel<<<1, 1024, 0, stream>>>(wB, wA, invL);  // (u3, u4)

    // 3) 60 FISTA iterations (t restarts at iter 50: y = h, t = 1)
    float t = 1.0f;
    const f16 *yin = h0f, *hin = h0f;
    int outSel = 1;                                 // 1 -> A set, 0 -> B set
    for (int n = 0; n < 60; ++n) {
        if (n == 50) { t = 1.0f; yin = hin; }
        const float tn = 0.5f * (1.0f + sqrtf(1.0f + 4.0f * t * t));
        const float cm = (t - 1.0f) / tn;
        f16* ho = outSel ? hA : hB;
        f16* yo = outSel ? yA : yB;
        fista160<<<dim3(KD / BNF, BATCH / BMF), 512, 0, stream>>>(
            yin, hin, bhiP, xthP, xtlP, invL, cm, ho, yo);
        t = tn;
        hin = ho; yin = yo;
        outSel ^= 1;
    }

    // 4) out = Wy @ h^T
    ypred_kernel<<<BATCH / 4, 256, 0, stream>>>(Wy, hin, out);
}